// Round 4
// baseline (1968.745 us; speedup 1.0000x reference)
//
#include <hip/hip_runtime.h>
#include <math.h>

#define HH  64
#define TT  2048
#define IND 7
#define NT  512

typedef float f4 __attribute__((ext_vector_type(4)));

// Pin a value into VGPRs: the loop consumes the asm output, which cannot be
// rematerialized as a load -> weights stay register-resident.
#define PIN4(v) asm volatile("" : "+v"(v))

__device__ __forceinline__ f4 fma4(f4 a, f4 b, f4 c) {
    return __builtin_elementwise_fma(a, b, c);
}

// sigmoid / tanh through a single exp: tanh(a) = 2*sigmoid(2a) - 1
__device__ __forceinline__ float gate_act(float a, bool is_tanh) {
    float z = is_tanh ? 2.0f * a : a;
    float e = __expf(-z);
    float sg = __fdividef(1.0f, 1.0f + e);
    return is_tanh ? fmaf(2.0f, sg, -1.0f) : sg;
}
__device__ __forceinline__ float tanh_s(float c) {
    float e = __expf(-2.0f * c);
    return fmaf(2.0f, __fdividef(1.0f, 1.0f + e), -1.0f);
}
// select the value whose xor-offset index is m (0:self,1:^16,2:^32,3:^48)
__device__ __forceinline__ float pick4(float a0, float a1, float a2, float a3, int m) {
    float lo = (m & 1) ? a1 : a0;
    float hi = (m & 1) ? a3 : a2;
    return (m & 2) ? hi : lo;
}

__global__ __launch_bounds__(NT) __attribute__((amdgpu_waves_per_eu(2, 2)))
void lstm2_fused(
    const float* __restrict__ x,     // (B,7,2048)
    const float* __restrict__ Wih0,  // (256,7)
    const float* __restrict__ Whh0,  // (256,64)
    const float* __restrict__ bih0, const float* __restrict__ bhh0,
    const float* __restrict__ Wih1,  // (256,64)
    const float* __restrict__ Whh1,  // (256,64)
    const float* __restrict__ bih1, const float* __restrict__ bhh1,
    const float* __restrict__ W1,    // (10,64)
    const float* __restrict__ b1v,   // (10)
    const float* __restrict__ gmma, const float* __restrict__ beta,
    const float* __restrict__ rm,   const float* __restrict__ rv,
    const float* __restrict__ W2,   // (1,10)
    const float* __restrict__ b2,   // (1)
    float* __restrict__ out)         // (B,1)
{
    const int b    = blockIdx.x;
    const int tid  = threadIdx.x;
    const int wave = tid >> 6;
    const int lane = tid & 63;
    const int s    = lane >> 4;        // sector: 0=i 1=f 2=g 3=o
    const int h    = lane & 1;         // k-half
    const int u    = (lane >> 1) & 7;  // unit within wave
    const int j    = (wave << 3) | u;  // hidden unit 0..63
    const int g    = (s << 6) | j;     // gate row 0..255

    __shared__ __align__(16) float xT[TT][8];     // 64 KB, xT[t][d], d=7 zero pad
    __shared__ __align__(16) float h0s[2][HH];
    __shared__ __align__(16) float h1s[2][HH];
    __shared__ float yv[10];

    // ---- stage x[b] transposed: global coalesced read, LDS [t][d] write ----
    {
        const float* xg = x + (size_t)b * (IND * TT);
        for (int i = tid; i < IND * TT; i += NT) {
            int d = i >> 11;          // /2048
            int t = i & (TT - 1);
            xT[t][d] = xg[i];
        }
        for (int t = tid; t < TT; t += NT) xT[t][7] = 0.0f;
        if (tid < HH) { h0s[1][tid] = 0.0f; h1s[1][tid] = 0.0f; }
    }

    // ---- per-thread weight half-rows into registers, PINNED (~100 VGPRs) ----
    f4 u0r[8], w1r[8], u1r[8];
    {
        const f4* p0 = (const f4*)(Whh0 + g * HH + 32 * h);
        const f4* p1 = (const f4*)(Wih1 + g * HH + 32 * h);
        const f4* p2 = (const f4*)(Whh1 + g * HH + 32 * h);
        #pragma unroll
        for (int r = 0; r < 8; ++r) {
            u0r[r] = p0[r]; w1r[r] = p1[r]; u1r[r] = p2[r];
            PIN4(u0r[r]); PIN4(w1r[r]); PIN4(u1r[r]);
        }
    }
    f4 xw;
    if (h == 0) { xw.x = Wih0[g*IND+0]; xw.y = Wih0[g*IND+1]; xw.z = Wih0[g*IND+2]; xw.w = Wih0[g*IND+3]; }
    else        { xw.x = Wih0[g*IND+4]; xw.y = Wih0[g*IND+5]; xw.z = Wih0[g*IND+6]; xw.w = 0.0f; }
    PIN4(xw);
    const float bg0 = (h == 0) ? (bih0[g] + bhh0[g]) : 0.0f;
    const float bg1 = (h == 0) ? (bih1[g] + bhh1[g]) : 0.0f;

    // h0q caches h0(t-1) chunk [32h .. 32h+31] across iterations
    f4 h0q[8];
    #pragma unroll
    for (int r = 0; r < 8; ++r) h0q[r] = (f4)(0.0f);

    float c0 = 0.0f, c1 = 0.0f;
    const bool is_t = (s == 2);
    const bool pub  = ((lane & 49) == 0);   // s==0 && h==0 lanes publish

    __syncthreads();

    for (int t = 0; t < TT; ++t) {
        const int p = t & 1;
        // ================= layer 0 (uses h0q = h0(t-1), registers) ==========
        f4 xq = *((const f4*)&xT[t][4 * h]);
        f4 a0; a0.x = bg0; a0.y = 0.f; a0.z = 0.f; a0.w = 0.f;
        a0 = fma4(xw, xq, a0);
        f4 a1 = (f4)(0.0f);
        #pragma unroll
        for (int r = 0; r < 8; r += 2) {
            a0 = fma4(u0r[r],     h0q[r],     a0);
            a1 = fma4(u0r[r + 1], h0q[r + 1], a1);
        }
        f4 am = a0 + a1;
        float ap = (am.x + am.y) + (am.z + am.w);
        float a  = ap + __shfl_xor(ap, 1);
        float act = gate_act(a, is_t);
        float v1 = __shfl_xor(act, 16);
        float v2 = __shfl_xor(act, 32);
        float v3 = __shfl_xor(act, 48);
        float iv = pick4(act, v1, v2, v3, s);
        float fv = pick4(act, v1, v2, v3, s ^ 1);
        float gv = pick4(act, v1, v2, v3, s ^ 2);
        float ov = pick4(act, v1, v2, v3, s ^ 3);
        c0 = fmaf(fv, c0, iv * gv);
        float h0new = ov * tanh_s(c0);
        if (pub) h0s[p][j] = h0new;
        __syncthreads();   // the only barrier per step

        // ===== layer 1: read h0(t) into h0q (reused next step) + h1(t-1) ====
        const f4* hp0 = (const f4*)&h0s[p][32 * h];
        const f4* hp1 = (const f4*)&h1s[p ^ 1][32 * h];
        f4 b0; b0.x = bg1; b0.y = 0.f; b0.z = 0.f; b0.w = 0.f;
        f4 b1 = (f4)(0.0f);
        #pragma unroll
        for (int r = 0; r < 8; ++r) {
            h0q[r] = hp0[r];
            b0 = fma4(w1r[r], h0q[r], b0);
            b1 = fma4(u1r[r], hp1[r], b1);
        }
        f4 bm = b0 + b1;
        float bp = (bm.x + bm.y) + (bm.z + bm.w);
        float ab = bp + __shfl_xor(bp, 1);
        float act1 = gate_act(ab, is_t);
        float q1 = __shfl_xor(act1, 16);
        float q2 = __shfl_xor(act1, 32);
        float q3 = __shfl_xor(act1, 48);
        float iv1 = pick4(act1, q1, q2, q3, s);
        float fv1 = pick4(act1, q1, q2, q3, s ^ 1);
        float gv1 = pick4(act1, q1, q2, q3, s ^ 2);
        float ov1 = pick4(act1, q1, q2, q3, s ^ 3);
        c1 = fmaf(fv1, c1, iv1 * gv1);
        float h1new = ov1 * tanh_s(c1);
        if (pub) h1s[p][j] = h1new;
        // no barrier here: h1s[p] / h0s[p^1] are only touched again after the
        // NEXT step's barrier (double-buffered), so one barrier/step suffices
    }
    __syncthreads();

    // ---- head: y = relu(bn(h1_last @ W1^T + b1)) @ W2^T + b2 ----
    if (tid < 10) {
        float y = b1v[tid];
        #pragma unroll
        for (int k = 0; k < HH; ++k) y += W1[tid * HH + k] * h1s[1][k];  // (TT-1)&1 == 1
        y = (y - rm[tid]) * rsqrtf(rv[tid] + 1e-5f) * gmma[tid] + beta[tid];
        y = fmaxf(y, 0.0f);
        yv[tid] = y * W2[tid];
    }
    __syncthreads();
    if (tid == 0) {
        float sacc = b2[0];
        #pragma unroll
        for (int k = 0; k < 10; ++k) sacc += yv[k];
        out[b] = sacc;
    }
}

extern "C" void kernel_launch(void* const* d_in, const int* in_sizes, int n_in,
                              void* d_out, int out_size, void* d_ws, size_t ws_size,
                              hipStream_t stream) {
    const float* x    = (const float*)d_in[0];
    const float* Wih0 = (const float*)d_in[1];
    const float* Whh0 = (const float*)d_in[2];
    const float* bih0 = (const float*)d_in[3];
    const float* bhh0 = (const float*)d_in[4];
    const float* Wih1 = (const float*)d_in[5];
    const float* Whh1 = (const float*)d_in[6];
    const float* bih1 = (const float*)d_in[7];
    const float* bhh1 = (const float*)d_in[8];
    const float* W1   = (const float*)d_in[9];
    const float* b1   = (const float*)d_in[10];
    const float* gmma = (const float*)d_in[11];
    const float* beta = (const float*)d_in[12];
    const float* rm   = (const float*)d_in[13];
    const float* rv   = (const float*)d_in[14];
    const float* W2   = (const float*)d_in[15];
    const float* b2   = (const float*)d_in[16];

    const int B = in_sizes[0] / (IND * TT);   // 256

    lstm2_fused<<<dim3(B), dim3(NT), 0, stream>>>(
        x, Wih0, Whh0, bih0, bhh0, Wih1, Whh1, bih1, bhh1,
        W1, b1, gmma, beta, rm, rv, W2, b2, (float*)d_out);
}

// Round 5
// 1620.982 us; speedup vs baseline: 1.2145x; 1.2145x over previous
//
#include <hip/hip_runtime.h>
#include <math.h>

#define HH  64
#define TT  2048
#define IND 7
#define NT  512

typedef float f4 __attribute__((ext_vector_type(4)));
typedef unsigned int u2v __attribute__((ext_vector_type(2)));

__device__ __forceinline__ f4 fma4(f4 a, f4 b, f4 c) {
    return __builtin_elementwise_fma(a, b, c);
}

// sum with lane^32 partner on the VALU pipe (v_permlane32_swap, gfx950)
__device__ __forceinline__ float sum_x32(float x) {
#if __has_builtin(__builtin_amdgcn_permlane32_swap)
    u2v r = __builtin_amdgcn_permlane32_swap(__float_as_uint(x), __float_as_uint(x), false, false);
    return __uint_as_float(r.x) + __uint_as_float(r.y);
#else
    return x + __shfl_xor(x, 32);
#endif
}

// quad_perm DPP: value from lane^1 / lane^2 / lane^3 within each 4-lane quad
template <int CTRL>
__device__ __forceinline__ float qperm(float x) {
    return __int_as_float(__builtin_amdgcn_update_dpp(0, __float_as_int(x), CTRL, 0xf, 0xf, true));
}
#define QP_X1 0xB1  // quad_perm(1,0,3,2)
#define QP_X2 0x4E  // quad_perm(2,3,0,1)
#define QP_X3 0x1B  // quad_perm(3,2,1,0)

__device__ __forceinline__ float tanh_s(float c) {
    float e = __expf(-2.0f * c);
    return fmaf(2.0f, __fdividef(1.0f, 1.0f + e), -1.0f);
}

__global__ __launch_bounds__(NT) __attribute__((amdgpu_waves_per_eu(2, 2)))
void lstm2_fused(
    const float* __restrict__ x,     // (B,7,2048)
    const float* __restrict__ Wih0,  // (256,7)
    const float* __restrict__ Whh0,  // (256,64)
    const float* __restrict__ bih0, const float* __restrict__ bhh0,
    const float* __restrict__ Wih1,  // (256,64)
    const float* __restrict__ Whh1,  // (256,64)
    const float* __restrict__ bih1, const float* __restrict__ bhh1,
    const float* __restrict__ W1,    // (10,64)
    const float* __restrict__ b1v,   // (10)
    const float* __restrict__ gmma, const float* __restrict__ beta,
    const float* __restrict__ rm,   const float* __restrict__ rv,
    const float* __restrict__ W2,   // (1,10)
    const float* __restrict__ b2,   // (1)
    float* __restrict__ out)         // (B,1)
{
    const int b    = blockIdx.x;
    const int tid  = threadIdx.x;
    const int wave = tid >> 6;
    const int lane = tid & 63;
    const int s    = lane & 3;          // sector 0:i 1:f 2:g 3:o  (quad-local!)
    const int q    = (lane >> 2) & 7;   // unit-within-wave
    const int kh   = lane >> 5;         // k-half
    const int j    = (wave << 3) | q;   // hidden unit 0..63
    const int g    = (s << 6) | j;      // gate row 0..255

    __shared__ __align__(16) float xT[TT][8];     // 64 KB, xT[t][d], d=7 zero pad
    __shared__ __align__(16) float h0s[2][HH];
    __shared__ __align__(16) float h1s[2][HH];
    __shared__ float yv[10];

    // ---- stage x[b] transposed: global coalesced read, LDS [t][d] write ----
    {
        const float* xg = x + (size_t)b * (IND * TT);
        for (int i = tid; i < IND * TT; i += NT) {
            int d = i >> 11;          // /2048
            int t = i & (TT - 1);
            xT[t][d] = xg[i];
        }
        for (int t = tid; t < TT; t += NT) xT[t][7] = 0.0f;
        if (tid < HH) { h0s[1][tid] = 0.0f; h1s[1][tid] = 0.0f; }
    }

    // ---- per-thread weight half-rows into registers (~100 regs) ----
    // tanh sector (s==2) pre-scaled by 2: z = 2a computed for free (exact, pow2)
    const float sc = (s == 2) ? 2.0f : 1.0f;
    f4 u0r[8], w1r[8], u1r[8];
    {
        const f4* p0 = (const f4*)(Whh0 + g * HH + 32 * kh);
        const f4* p1 = (const f4*)(Wih1 + g * HH + 32 * kh);
        const f4* p2 = (const f4*)(Whh1 + g * HH + 32 * kh);
        #pragma unroll
        for (int r = 0; r < 8; ++r) {
            u0r[r] = p0[r] * sc; w1r[r] = p1[r] * sc; u1r[r] = p2[r] * sc;
        }
    }
    f4 xw;
    if (kh == 0) { xw.x = Wih0[g*IND+0]; xw.y = Wih0[g*IND+1]; xw.z = Wih0[g*IND+2]; xw.w = Wih0[g*IND+3]; }
    else         { xw.x = Wih0[g*IND+4]; xw.y = Wih0[g*IND+5]; xw.z = Wih0[g*IND+6]; xw.w = 0.0f; }
    xw *= sc;
    const float bg0 = (kh == 0) ? (bih0[g] + bhh0[g]) * sc : 0.0f;
    const float bg1 = (kh == 0) ? (bih1[g] + bhh1[g]) * sc : 0.0f;

    f4 h0q[8];                       // register cache of h0(t-1) chunk
    #pragma unroll
    for (int r = 0; r < 8; ++r) h0q[r] = (f4)(0.0f);

    float c0 = 0.0f, c1 = 0.0f;
    const bool is_t = (s == 2);
    const bool sb0  = (s & 1) != 0;
    const bool sb1  = (s & 2) != 0;
    const bool pubL = ((lane & 35) == 0);   // s==0 && kh==0

    __syncthreads();

    f4 xq = *((const f4*)&xT[0][4 * kh]);   // prefetched x(t)

    for (int t = 0; t < TT; ++t) {
        const int p = t & 1;
        // ================= layer 0 (h0q = h0(t-1) in registers) =============
        f4 A0; A0.x = bg0; A0.y = 0.f; A0.z = 0.f; A0.w = 0.f;
        A0 = fma4(xw, xq, A0);
        f4 A1 = (f4)(0.0f);
        #pragma unroll
        for (int r = 0; r < 8; r += 2) {
            A0 = fma4(u0r[r],     h0q[r],     A0);
            A1 = fma4(u0r[r + 1], h0q[r + 1], A1);
        }
        f4 am = A0 + A1;
        float ap = (am.x + am.y) + (am.z + am.w);
        float a  = sum_x32(ap);                       // k-half reduce, VALU
        float e  = __expf(-a);
        float sg = __fdividef(1.0f, 1.0f + e);
        float act = is_t ? fmaf(2.0f, sg, -1.0f) : sg;
        // gather i,f,g,o within the quad via DPP (VALU pipe)
        float v1 = qperm<QP_X1>(act);
        float v2 = qperm<QP_X2>(act);
        float v3 = qperm<QP_X3>(act);
        float lo  = sb0 ? v1 : act, hi  = sb0 ? v3 : v2;
        float lo1 = sb0 ? act : v1, hi1 = sb0 ? v2 : v3;
        float iv = sb1 ? hi  : lo;
        float fv = sb1 ? hi1 : lo1;
        float gv = sb1 ? lo  : hi;
        float ov = sb1 ? lo1 : hi1;
        c0 = fmaf(fv, c0, iv * gv);
        float h0n = ov * tanh_s(c0);
        if (pubL) h0s[p][j] = h0n;
        __syncthreads();   // the only barrier per step

        // prefetch next x(t+1) (xT is read-only; wrap avoids OOB at t=2047)
        xq = *((const f4*)&xT[(t + 1) & (TT - 1)][4 * kh]);

        // ===== layer 1: read h0(t) (cache for next step) + h1(t-1) ==========
        const f4* hp0 = (const f4*)&h0s[p][32 * kh];
        const f4* hp1 = (const f4*)&h1s[p ^ 1][32 * kh];
        f4 B0; B0.x = bg1; B0.y = 0.f; B0.z = 0.f; B0.w = 0.f;
        f4 B1 = (f4)(0.0f);
        #pragma unroll
        for (int r = 0; r < 8; ++r) {
            f4 hv = hp0[r];
            h0q[r] = hv;
            B0 = fma4(w1r[r], hv,     B0);
            B1 = fma4(u1r[r], hp1[r], B1);
        }
        f4 bm = B0 + B1;
        float bp = (bm.x + bm.y) + (bm.z + bm.w);
        float ab = sum_x32(bp);
        float e1  = __expf(-ab);
        float sg1 = __fdividef(1.0f, 1.0f + e1);
        float act1 = is_t ? fmaf(2.0f, sg1, -1.0f) : sg1;
        float w1v = qperm<QP_X1>(act1);
        float w2v = qperm<QP_X2>(act1);
        float w3v = qperm<QP_X3>(act1);
        float lo_  = sb0 ? w1v : act1, hi_  = sb0 ? w3v : w2v;
        float lo1_ = sb0 ? act1 : w1v, hi1_ = sb0 ? w2v : w3v;
        float iv1 = sb1 ? hi_  : lo_;
        float fv1 = sb1 ? hi1_ : lo1_;
        float gv1 = sb1 ? lo_  : hi_;
        float ov1 = sb1 ? lo1_ : hi1_;
        c1 = fmaf(fv1, c1, iv1 * gv1);
        float h1n = ov1 * tanh_s(c1);
        if (pubL) h1s[p][j] = h1n;
        // no barrier: h1s[p] / h0s[p^1] only touched after the NEXT barrier
    }
    __syncthreads();

    // ---- head: y = relu(bn(h1_last @ W1^T + b1)) @ W2^T + b2 ----
    if (tid < 10) {
        float y = b1v[tid];
        #pragma unroll
        for (int k = 0; k < HH; ++k) y += W1[tid * HH + k] * h1s[1][k];  // (TT-1)&1 == 1
        y = (y - rm[tid]) * rsqrtf(rv[tid] + 1e-5f) * gmma[tid] + beta[tid];
        y = fmaxf(y, 0.0f);
        yv[tid] = y * W2[tid];
    }
    __syncthreads();
    if (tid == 0) {
        float sacc = b2[0];
        #pragma unroll
        for (int k = 0; k < 10; ++k) sacc += yv[k];
        out[b] = sacc;
    }
}

extern "C" void kernel_launch(void* const* d_in, const int* in_sizes, int n_in,
                              void* d_out, int out_size, void* d_ws, size_t ws_size,
                              hipStream_t stream) {
    const float* x    = (const float*)d_in[0];
    const float* Wih0 = (const float*)d_in[1];
    const float* Whh0 = (const float*)d_in[2];
    const float* bih0 = (const float*)d_in[3];
    const float* bhh0 = (const float*)d_in[4];
    const float* Wih1 = (const float*)d_in[5];
    const float* Whh1 = (const float*)d_in[6];
    const float* bih1 = (const float*)d_in[7];
    const float* bhh1 = (const float*)d_in[8];
    const float* W1   = (const float*)d_in[9];
    const float* b1   = (const float*)d_in[10];
    const float* gmma = (const float*)d_in[11];
    const float* beta = (const float*)d_in[12];
    const float* rm   = (const float*)d_in[13];
    const float* rv   = (const float*)d_in[14];
    const float* W2   = (const float*)d_in[15];
    const float* b2   = (const float*)d_in[16];

    const int B = in_sizes[0] / (IND * TT);   // 256

    lstm2_fused<<<dim3(B), dim3(NT), 0, stream>>>(
        x, Wih0, Whh0, bih0, bhh0, Wih1, Whh1, bih1, bhh1,
        W1, b1, gmma, beta, rm, rv, W2, b2, (float*)d_out);
}

// Round 6
// 1508.888 us; speedup vs baseline: 1.3048x; 1.0743x over previous
//
#include <hip/hip_runtime.h>
#include <math.h>

#define HH  64
#define TT  2048
#define IND 7
#define NT  512

typedef float f2 __attribute__((ext_vector_type(2)));
typedef float f4 __attribute__((ext_vector_type(4)));
typedef unsigned int u2v __attribute__((ext_vector_type(2)));

#define LO2(v) __builtin_shufflevector(v, v, 0, 1)
#define HI2(v) __builtin_shufflevector(v, v, 2, 3)

// forced packed fp32 FMA: acc = a*b + acc (2 FLOP/instr on the VALU)
__device__ __forceinline__ void pkfma(f2& acc, f2 a, f2 b) {
    asm("v_pk_fma_f32 %0, %1, %2, %0" : "+v"(acc) : "v"(a), "v"(b));
}

// sum with lane^32 partner on the VALU pipe (v_permlane32_swap, gfx950)
__device__ __forceinline__ float sum_x32(float x) {
#if __has_builtin(__builtin_amdgcn_permlane32_swap)
    u2v r = __builtin_amdgcn_permlane32_swap(__float_as_uint(x), __float_as_uint(x), false, false);
    return __uint_as_float(r.x) + __uint_as_float(r.y);
#else
    return x + __shfl_xor(x, 32);
#endif
}

template <int CTRL>
__device__ __forceinline__ float qperm(float x) {
    return __int_as_float(__builtin_amdgcn_update_dpp(0, __float_as_int(x), CTRL, 0xf, 0xf, true));
}
#define QP_X1 0xB1  // quad_perm(1,0,3,2)
#define QP_X2 0x4E  // quad_perm(2,3,0,1)
#define QP_X3 0x1B  // quad_perm(3,2,1,0)

__device__ __forceinline__ float gact(float a, bool is_t) {
    float e  = __expf(-a);
    float sg = __fdividef(1.0f, 1.0f + e);
    return is_t ? fmaf(2.0f, sg, -1.0f) : sg;
}
__device__ __forceinline__ float tanh_s(float c) {
    float e = __expf(-2.0f * c);
    return fmaf(2.0f, __fdividef(1.0f, 1.0f + e), -1.0f);
}

struct G4 { float i, f, g, o; };
__device__ __forceinline__ G4 gather4(float act, bool sb0, bool sb1) {
    float v1 = qperm<QP_X1>(act);
    float v2 = qperm<QP_X2>(act);
    float v3 = qperm<QP_X3>(act);
    float lo  = sb0 ? v1 : act, hi  = sb0 ? v3 : v2;
    float lo1 = sb0 ? act : v1, hi1 = sb0 ? v2 : v3;
    G4 r;
    r.i = sb1 ? hi  : lo;
    r.f = sb1 ? hi1 : lo1;
    r.g = sb1 ? lo  : hi;
    r.o = sb1 ? lo1 : hi1;
    return r;
}

__global__ __launch_bounds__(NT) __attribute__((amdgpu_waves_per_eu(2, 2)))
void lstm2_fused(
    const float* __restrict__ x,     // (B,7,2048)
    const float* __restrict__ Wih0,  // (256,7)
    const float* __restrict__ Whh0,  // (256,64)
    const float* __restrict__ bih0, const float* __restrict__ bhh0,
    const float* __restrict__ Wih1,  // (256,64)
    const float* __restrict__ Whh1,  // (256,64)
    const float* __restrict__ bih1, const float* __restrict__ bhh1,
    const float* __restrict__ W1,    // (10,64)
    const float* __restrict__ b1v,   // (10)
    const float* __restrict__ gmma, const float* __restrict__ beta,
    const float* __restrict__ rm,   const float* __restrict__ rv,
    const float* __restrict__ W2,   // (1,10)
    const float* __restrict__ b2,   // (1)
    float* __restrict__ out)         // (B,1)
{
    const int b    = blockIdx.x;
    const int tid  = threadIdx.x;
    const int wave = tid >> 6;
    const int lane = tid & 63;
    const int grp  = wave >> 2;         // 0: layer-0 waves, 1: layer-1 waves
    const int wv   = wave & 3;
    const int s    = lane & 3;          // sector 0:i 1:f 2:g 3:o (quad-local)
    const int u    = (lane >> 2) & 7;
    const int kh   = lane >> 5;         // k-half
    const int j    = wv * 8 + u;        // first unit (0..31)
    const int j2   = j + 32;            // second unit
    const int g    = (s << 6) | j;
    const int g2   = (s << 6) | j2;

    __shared__ __align__(16) float xT[TT][8];     // 64 KB
    __shared__ __align__(16) float h0s[2][HH];
    __shared__ __align__(16) float h1s[2][HH];
    __shared__ float yv[10];

    // ---- stage x[b] transposed ----
    {
        const float* xg = x + (size_t)b * (IND * TT);
        for (int i = tid; i < IND * TT; i += NT) {
            int d = i >> 11;
            int t = i & (TT - 1);
            xT[t][d] = xg[i];
        }
        for (int t = tid; t < TT; t += NT) xT[t][7] = 0.0f;
        if (tid < HH) { h0s[1][tid] = 0.0f; h1s[0][tid] = 0.0f; h1s[1][tid] = 0.0f; }
    }

    const float sc   = (s == 2) ? 2.0f : 1.0f;   // tanh sector pre-scale (exact)
    const bool  is_t = (s == 2);
    const bool  sb0  = (s & 1) != 0;
    const bool  sb1  = (s & 2) != 0;
    const bool  pubL = ((lane & 35) == 0);       // s==0 && kh==0

    __syncthreads();

    if (grp == 0) {
        // =================== LAYER-0 GROUP: computes h0(k) at tick k ===================
        f2 wA[16], wB[16];
        {
            const f4* pA = (const f4*)(Whh0 + g  * HH + 32 * kh);
            const f4* pB = (const f4*)(Whh0 + g2 * HH + 32 * kh);
            #pragma unroll
            for (int r = 0; r < 8; ++r) {
                f4 a = pA[r] * sc; f4 bq = pB[r] * sc;
                wA[2*r] = LO2(a);  wA[2*r+1] = HI2(a);
                wB[2*r] = LO2(bq); wB[2*r+1] = HI2(bq);
            }
        }
        f2 xwA0, xwA1, xwB0, xwB1;
        if (kh == 0) {
            xwA0 = f2{Wih0[g*IND+0],  Wih0[g*IND+1]};  xwA1 = f2{Wih0[g*IND+2],  Wih0[g*IND+3]};
            xwB0 = f2{Wih0[g2*IND+0], Wih0[g2*IND+1]}; xwB1 = f2{Wih0[g2*IND+2], Wih0[g2*IND+3]};
        } else {
            xwA0 = f2{Wih0[g*IND+4],  Wih0[g*IND+5]};  xwA1 = f2{Wih0[g*IND+6],  0.0f};
            xwB0 = f2{Wih0[g2*IND+4], Wih0[g2*IND+5]}; xwB1 = f2{Wih0[g2*IND+6], 0.0f};
        }
        xwA0 *= sc; xwA1 *= sc; xwB0 *= sc; xwB1 *= sc;
        const float bgA = (kh == 0) ? (bih0[g]  + bhh0[g])  * sc : 0.0f;
        const float bgB = (kh == 0) ? (bih0[g2] + bhh0[g2]) * sc : 0.0f;

        float c0A = 0.0f, c0B = 0.0f;
        f4 xq = *((const f4*)&xT[0][4 * kh]);

        for (int tick = 0; tick <= TT; ++tick) {
            const int p = tick & 1;
            if (tick < TT) {
                const f4* hp = (const f4*)&h0s[p ^ 1][32 * kh];
                f2 aA0 = f2{bgA, 0.f}, aA1 = f2{0.f, 0.f};
                f2 aB0 = f2{bgB, 0.f}, aB1 = f2{0.f, 0.f};
                #pragma unroll
                for (int r = 0; r < 8; ++r) {
                    f4 hv = hp[r];
                    f2 hl = LO2(hv), hh = HI2(hv);
                    pkfma(aA0, wA[2*r], hl); pkfma(aA1, wA[2*r+1], hh);
                    pkfma(aB0, wB[2*r], hl); pkfma(aB1, wB[2*r+1], hh);
                }
                pkfma(aA0, xwA0, LO2(xq)); pkfma(aA1, xwA1, HI2(xq));
                pkfma(aB0, xwB0, LO2(xq)); pkfma(aB1, xwB1, HI2(xq));
                f2 sA = aA0 + aA1;  f2 sB = aB0 + aB1;
                float aAf = sum_x32(sA.x + sA.y);
                float aBf = sum_x32(sB.x + sB.y);
                float actA = gact(aAf, is_t);
                float actB = gact(aBf, is_t);
                G4 gA = gather4(actA, sb0, sb1);
                G4 gB = gather4(actB, sb0, sb1);
                c0A = fmaf(gA.f, c0A, gA.i * gA.g);
                c0B = fmaf(gB.f, c0B, gB.i * gB.g);
                float h0nA = gA.o * tanh_s(c0A);
                float h0nB = gB.o * tanh_s(c0B);
                if (pubL) { h0s[p][j] = h0nA; h0s[p][j2] = h0nB; }
                xq = *((const f4*)&xT[(tick + 1) & (TT - 1)][4 * kh]);
            }
            __syncthreads();
        }
    } else {
        // ============ LAYER-1 GROUP: computes h1(k-1) at tick k (one behind) ============
        f2 w1A[16], u1A[16], w1B[16], u1B[16];
        {
            const f4* pA = (const f4*)(Wih1 + g  * HH + 32 * kh);
            const f4* pB = (const f4*)(Wih1 + g2 * HH + 32 * kh);
            const f4* qA = (const f4*)(Whh1 + g  * HH + 32 * kh);
            const f4* qB = (const f4*)(Whh1 + g2 * HH + 32 * kh);
            #pragma unroll
            for (int r = 0; r < 8; ++r) {
                f4 a = pA[r] * sc; f4 bq = pB[r] * sc;
                f4 cq = qA[r] * sc; f4 dq = qB[r] * sc;
                w1A[2*r] = LO2(a);  w1A[2*r+1] = HI2(a);
                w1B[2*r] = LO2(bq); w1B[2*r+1] = HI2(bq);
                u1A[2*r] = LO2(cq); u1A[2*r+1] = HI2(cq);
                u1B[2*r] = LO2(dq); u1B[2*r+1] = HI2(dq);
            }
        }
        const float bgA = (kh == 0) ? (bih1[g]  + bhh1[g])  * sc : 0.0f;
        const float bgB = (kh == 0) ? (bih1[g2] + bhh1[g2]) * sc : 0.0f;

        float c1A = 0.0f, c1B = 0.0f;

        for (int tick = 0; tick <= TT; ++tick) {
            const int p = tick & 1;
            if (tick > 0) {
                const f4* hp0 = (const f4*)&h0s[p ^ 1][32 * kh];   // h0(tick-1)
                const f4* hp1 = (const f4*)&h1s[p ^ 1][32 * kh];   // h1(tick-2)
                f2 aA0 = f2{bgA, 0.f}, aA1 = f2{0.f, 0.f};
                f2 aB0 = f2{bgB, 0.f}, aB1 = f2{0.f, 0.f};
                #pragma unroll
                for (int r = 0; r < 8; ++r) {
                    f4 h0v = hp0[r];
                    f4 h1v = hp1[r];
                    f2 l0 = LO2(h0v), h0h = HI2(h0v);
                    f2 l1 = LO2(h1v), h1h = HI2(h1v);
                    pkfma(aA0, w1A[2*r], l0); pkfma(aA1, w1A[2*r+1], h0h);
                    pkfma(aA0, u1A[2*r], l1); pkfma(aA1, u1A[2*r+1], h1h);
                    pkfma(aB0, w1B[2*r], l0); pkfma(aB1, w1B[2*r+1], h0h);
                    pkfma(aB0, u1B[2*r], l1); pkfma(aB1, u1B[2*r+1], h1h);
                }
                f2 sA = aA0 + aA1;  f2 sB = aB0 + aB1;
                float aAf = sum_x32(sA.x + sA.y);
                float aBf = sum_x32(sB.x + sB.y);
                float actA = gact(aAf, is_t);
                float actB = gact(aBf, is_t);
                G4 gA = gather4(actA, sb0, sb1);
                G4 gB = gather4(actB, sb0, sb1);
                c1A = fmaf(gA.f, c1A, gA.i * gA.g);
                c1B = fmaf(gB.f, c1B, gB.i * gB.g);
                float h1nA = gA.o * tanh_s(c1A);
                float h1nB = gB.o * tanh_s(c1B);
                if (pubL) { h1s[p][j] = h1nA; h1s[p][j2] = h1nB; }
            }
            __syncthreads();
        }
    }

    // h1(TT-1) was stored at tick TT into h1s[TT&1] = h1s[0]
    if (tid < 10) {
        float y = b1v[tid];
        #pragma unroll
        for (int k = 0; k < HH; ++k) y += W1[tid * HH + k] * h1s[0][k];
        y = (y - rm[tid]) * rsqrtf(rv[tid] + 1e-5f) * gmma[tid] + beta[tid];
        y = fmaxf(y, 0.0f);
        yv[tid] = y * W2[tid];
    }
    __syncthreads();
    if (tid == 0) {
        float sacc = b2[0];
        #pragma unroll
        for (int k = 0; k < 10; ++k) sacc += yv[k];
        out[b] = sacc;
    }
}

extern "C" void kernel_launch(void* const* d_in, const int* in_sizes, int n_in,
                              void* d_out, int out_size, void* d_ws, size_t ws_size,
                              hipStream_t stream) {
    const float* x    = (const float*)d_in[0];
    const float* Wih0 = (const float*)d_in[1];
    const float* Whh0 = (const float*)d_in[2];
    const float* bih0 = (const float*)d_in[3];
    const float* bhh0 = (const float*)d_in[4];
    const float* Wih1 = (const float*)d_in[5];
    const float* Whh1 = (const float*)d_in[6];
    const float* bih1 = (const float*)d_in[7];
    const float* bhh1 = (const float*)d_in[8];
    const float* W1   = (const float*)d_in[9];
    const float* b1   = (const float*)d_in[10];
    const float* gmma = (const float*)d_in[11];
    const float* beta = (const float*)d_in[12];
    const float* rm   = (const float*)d_in[13];
    const float* rv   = (const float*)d_in[14];
    const float* W2   = (const float*)d_in[15];
    const float* b2   = (const float*)d_in[16];

    const int B = in_sizes[0] / (IND * TT);   // 256

    lstm2_fused<<<dim3(B), dim3(NT), 0, stream>>>(
        x, Wih0, Whh0, bih0, bhh0, Wih1, Whh1, bih1, bhh1,
        W1, b1, gmma, beta, rm, rv, W2, b2, (float*)d_out);
}